// Round 1
// baseline (739.988 us; speedup 1.0000x reference)
//
#include <hip/hip_runtime.h>

typedef unsigned short u16;
typedef __attribute__((ext_vector_type(8))) __bf16 bf16x8;
typedef __attribute__((ext_vector_type(4))) float f32x4;
typedef __attribute__((ext_vector_type(4))) unsigned short u16x4;

// ---------- bf16 split helpers ----------
static __device__ __forceinline__ u16 f2bf(float f) {
  union { float f; unsigned u; } v; v.f = f;
  unsigned r = v.u + 0x7FFFu + ((v.u >> 16) & 1u);   // RNE
  return (u16)(r >> 16);
}
static __device__ __forceinline__ float bf2f(u16 h) {
  union { unsigned u; float f; } v; v.u = ((unsigned)h) << 16;
  return v.f;
}
static __device__ __forceinline__ f32x4 mfma16(bf16x8 a, bf16x8 b, f32x4 c) {
  return __builtin_amdgcn_mfma_f32_16x16x32_bf16(a, b, c, 0, 0, 0);
}

// ============================================================
// Kernel 1: transpose + hi/lo split of Wq, Wk, Wv (256x256 each)
// Output layout (u16): [wqt_h][wqt_l][wkt_h][wkt_l][wvt_h][wvt_l], each 65536
// WT[h][e] = W[e][h]
// ============================================================
__global__ __launch_bounds__(256) void prep_w_kernel(
    const float* __restrict__ Wq, const float* __restrict__ Wk,
    const float* __restrict__ Wv, u16* __restrict__ wout) {
  int idx = blockIdx.x * 256 + threadIdx.x;   // 0..196607
  int mm = idx >> 16;
  int o  = idx & 65535;
  int h = o >> 8, e = o & 255;
  const float* W = (mm == 0) ? Wq : ((mm == 1) ? Wk : Wv);
  float v = W[e * 256 + h];
  u16 hi = f2bf(v);
  u16 lo = f2bf(v - bf2f(hi));
  wout[(size_t)mm * 131072 + o] = hi;
  wout[(size_t)mm * 131072 + 65536 + o] = lo;
}

// ============================================================
// Kernel 2: QKV projection.
// Grid: 1024 blocks x 256 threads; each block = 64 tokens (one batch only,
// since 64 | 1024). Computes:
//   qh/ql, kh/kl : [B*S][256] bf16 hi/lo      (row-major, A-frag friendly)
//   vT           : [B][256][1024] bf16        (v transposed, B-frag friendly)
// 3-term split MFMA for ~fp32 accuracy.
// ============================================================
__global__ __launch_bounds__(256) void proj_kernel(
    const float* __restrict__ x, const float* __restrict__ bq,
    const float* __restrict__ bk, const float* __restrict__ bv,
    const u16* __restrict__ wqt_h, const u16* __restrict__ wqt_l,
    const u16* __restrict__ wkt_h, const u16* __restrict__ wkt_l,
    const u16* __restrict__ wvt_h, const u16* __restrict__ wvt_l,
    u16* __restrict__ qh_g, u16* __restrict__ ql_g,
    u16* __restrict__ kh_g, u16* __restrict__ kl_g,
    u16* __restrict__ vt_g) {
  __shared__ __align__(16) char xlds[65536];   // xh [64][256] bf16 + xl
  char* xh = xlds;
  char* xl = xlds + 32768;
  const int tid = threadIdx.x;
  const int l = tid & 63, w = tid >> 6;
  const int l15 = l & 15, l4 = l >> 4;
  const int blk = blockIdx.x;
  const size_t tok0 = (size_t)blk * 64;
  const int kbyte = l4 * 16;

  // ---- stage x tile [64][256] fp32 -> split hi/lo bf16 LDS (XOR swizzle) ----
  #pragma unroll
  for (int i = 0; i < 16; i++) {
    int c = tid + i * 256;            // 0..4095
    int row = c >> 6, col4 = c & 63;  // row 0..63, col4 = float4 index
    float4 f = *(const float4*)(x + ((tok0 + row) << 8) + col4 * 4);
    u16x4 hv, lv;
    hv.x = f2bf(f.x); lv.x = f2bf(f.x - bf2f(hv.x));
    hv.y = f2bf(f.y); lv.y = f2bf(f.y - bf2f(hv.y));
    hv.z = f2bf(f.z); lv.z = f2bf(f.z - bf2f(hv.z));
    hv.w = f2bf(f.w); lv.w = f2bf(f.w - bf2f(hv.w));
    int off = ((row << 9) + (col4 << 3)) ^ ((row & 7) << 4);
    *(u16x4*)(xh + off) = hv;
    *(u16x4*)(xl + off) = lv;
  }
  __syncthreads();

  auto XF = [&](const char* base, int tok, int kk) -> bf16x8 {
    int off = ((tok << 9) + kk * 64 + kbyte) ^ ((tok & 7) << 4);
    return *(const bf16x8*)(base + off);
  };

  // ---- Q and K projections (each wave: 16 token rows x 256 cols) ----
  #pragma unroll
  for (int m = 0; m < 2; m++) {
    const u16* wth = m ? wkt_h : wqt_h;
    const u16* wtl = m ? wkt_l : wqt_l;
    const float* bias = m ? bk : bq;
    u16* oh = m ? kh_g : qh_g;
    u16* ol = m ? kl_g : ql_g;
    f32x4 acc[16];
    #pragma unroll
    for (int i = 0; i < 16; i++) acc[i] = (f32x4){0.f, 0.f, 0.f, 0.f};
    const int atok = w * 16 + l15;
    for (int kk = 0; kk < 8; kk++) {
      bf16x8 ah = XF(xh, atok, kk);
      bf16x8 al = XF(xl, atok, kk);
      #pragma unroll
      for (int ht = 0; ht < 16; ht++) {
        size_t woff = ((size_t)(ht * 16 + l15) << 8) + kk * 32 + l4 * 8;
        bf16x8 bh = *(const bf16x8*)(wth + woff);
        bf16x8 bl = *(const bf16x8*)(wtl + woff);
        acc[ht] = mfma16(ah, bh, acc[ht]);
        acc[ht] = mfma16(al, bh, acc[ht]);
        acc[ht] = mfma16(ah, bl, acc[ht]);
      }
    }
    #pragma unroll
    for (int ht = 0; ht < 16; ht++) {
      int h = ht * 16 + l15;
      float bb = bias[h];
      #pragma unroll
      for (int j = 0; j < 4; j++) {
        size_t tok = tok0 + w * 16 + l4 * 4 + j;
        float v = acc[ht][j] + bb;
        u16 hi = f2bf(v);
        u16 lo = f2bf(v - bf2f(hi));
        oh[(tok << 8) + h] = hi;
        ol[(tok << 8) + h] = lo;
      }
    }
  }

  // ---- vT projection: vT[d][t] = sum_e WvT[d][e] * x[t][e] + bv[d] ----
  // Each wave: d rows [64w, 64w+64) x 64 tokens.
  {
    f32x4 acc[16];
    #pragma unroll
    for (int i = 0; i < 16; i++) acc[i] = (f32x4){0.f, 0.f, 0.f, 0.f};
    for (int kk = 0; kk < 8; kk++) {
      bf16x8 bhf[4], blf[4];
      #pragma unroll
      for (int tt = 0; tt < 4; tt++) {
        bhf[tt] = XF(xh, tt * 16 + l15, kk);
        blf[tt] = XF(xl, tt * 16 + l15, kk);
      }
      #pragma unroll
      for (int dt = 0; dt < 4; dt++) {
        size_t woff = ((size_t)(w * 64 + dt * 16 + l15) << 8) + kk * 32 + l4 * 8;
        bf16x8 ah = *(const bf16x8*)(wvt_h + woff);
        bf16x8 al = *(const bf16x8*)(wvt_l + woff);
        #pragma unroll
        for (int tt = 0; tt < 4; tt++) {
          acc[dt * 4 + tt] = mfma16(ah, bhf[tt], acc[dt * 4 + tt]);
          acc[dt * 4 + tt] = mfma16(al, bhf[tt], acc[dt * 4 + tt]);
          acc[dt * 4 + tt] = mfma16(ah, blf[tt], acc[dt * 4 + tt]);
        }
      }
    }
    const int b = blk >> 4;
    const int s0 = (blk & 15) * 64;
    #pragma unroll
    for (int dt = 0; dt < 4; dt++) {
      #pragma unroll
      for (int j = 0; j < 4; j++) {
        int d = w * 64 + dt * 16 + l4 * 4 + j;
        float bb = bv[d];
        #pragma unroll
        for (int tt = 0; tt < 4; tt++) {
          float v = acc[dt * 4 + tt][j] + bb;
          vt_g[(((size_t)(b * 256 + d)) << 10) + s0 + tt * 16 + l15] = f2bf(v);
        }
      }
    }
  }
}

// ============================================================
// Kernel 3: flash attention (unscaled, non-causal).
// Grid: (16 q-tiles, 64 batches) x 256 threads.
// WG = 64 q rows; each wave owns 16 q rows. KVBLK = 32.
// K hi/lo + vT tiles staged in LDS (XOR bank swizzle).
// Scores: 3-term split MFMA (qh*kh + ql*kh + qh*kl), fp32 accum.
// PV: single bf16 MFMA.
// ============================================================
__global__ __launch_bounds__(256) void attn_kernel(
    const u16* __restrict__ qh_g, const u16* __restrict__ ql_g,
    const u16* __restrict__ kh_g, const u16* __restrict__ kl_g,
    const u16* __restrict__ vt_g, float* __restrict__ out) {
  __shared__ __align__(16) char lds[53248];
  char* kh_lds = lds;            // [32][256] bf16 = 16KB (swizzled)
  char* kl_lds = lds + 16384;    // 16KB
  char* vt_lds = lds + 32768;    // [256][32] bf16 = 16KB (swizzled)
  char* p_lds  = lds + 49152;    // 4 waves x [16][32] bf16 = 4KB (swizzled)

  const int tid = threadIdx.x;
  const int l = tid & 63, w = tid >> 6;
  const int l15 = l & 15, l4 = l >> 4;
  const int bx = blockIdx.x;     // q tile
  const int b  = blockIdx.y;     // batch
  const int kbyte = l4 * 16;

  // ---- load this wave's Q fragments (16 rows, hi/lo) ----
  const int q0 = bx * 64 + w * 16;
  const size_t qtok = (size_t)(b * 1024 + q0 + l15);
  const u16* qhp = qh_g + (qtok << 8) + l4 * 8;
  const u16* qlp = ql_g + (qtok << 8) + l4 * 8;
  bf16x8 qfh[8], qfl[8];
  #pragma unroll
  for (int kk = 0; kk < 8; kk++) {
    qfh[kk] = *(const bf16x8*)(qhp + kk * 32);
    qfl[kk] = *(const bf16x8*)(qlp + kk * 32);
  }

  f32x4 O[16];
  #pragma unroll
  for (int i = 0; i < 16; i++) O[i] = (f32x4){0.f, 0.f, 0.f, 0.f};
  float mrow[4] = {-1e30f, -1e30f, -1e30f, -1e30f};
  float lrow[4] = {0.f, 0.f, 0.f, 0.f};

  const u16* khb = kh_g + ((size_t)b << 18);
  const u16* klb = kl_g + ((size_t)b << 18);
  const u16* vtb = vt_g + ((size_t)b << 18);
  char* pw = p_lds + w * 1024;

  for (int t0 = 0; t0 < 1024; t0 += 32) {
    __syncthreads();   // previous tile fully consumed
    // ---- stage K hi/lo [32][256] + vT [256][32] (XOR swizzled) ----
    #pragma unroll
    for (int i = 0; i < 4; i++) {
      int c = tid + i * 256;
      int row = c >> 5, sl = c & 31;
      int4 dk = *(const int4*)(khb + (((size_t)(t0 + row)) << 8) + sl * 8);
      *(int4*)(kh_lds + (((row << 9) + (sl << 4)) ^ ((row & 7) << 4))) = dk;
      int4 dl = *(const int4*)(klb + (((size_t)(t0 + row)) << 8) + sl * 8);
      *(int4*)(kl_lds + (((row << 9) + (sl << 4)) ^ ((row & 7) << 4))) = dl;
      int d = c >> 2, vs = c & 3;
      int4 dv = *(const int4*)(vtb + (((size_t)d) << 10) + t0 + vs * 8);
      *(int4*)(vt_lds + (((d << 6) + (vs << 4)) ^ ((d & 7) << 4))) = dv;
    }
    __syncthreads();

    // ---- scores: S[16q][32t], 3-term split ----
    f32x4 sa = (f32x4){0.f, 0.f, 0.f, 0.f};
    f32x4 sb = (f32x4){0.f, 0.f, 0.f, 0.f};
    for (int kk = 0; kk < 8; kk++) {
      int ko = kk * 64 + kbyte;
      int r0 = l15, r1 = l15 + 16;
      int sw = (l15 & 7) << 4;
      bf16x8 bh0 = *(const bf16x8*)(kh_lds + (((r0 << 9) + ko) ^ sw));
      bf16x8 bl0 = *(const bf16x8*)(kl_lds + (((r0 << 9) + ko) ^ sw));
      bf16x8 bh1 = *(const bf16x8*)(kh_lds + (((r1 << 9) + ko) ^ sw));
      bf16x8 bl1 = *(const bf16x8*)(kl_lds + (((r1 << 9) + ko) ^ sw));
      sa = mfma16(qfh[kk], bh0, sa);
      sa = mfma16(qfl[kk], bh0, sa);
      sa = mfma16(qfh[kk], bl0, sa);
      sb = mfma16(qfh[kk], bh1, sb);
      sb = mfma16(qfl[kk], bh1, sb);
      sb = mfma16(qfh[kk], bl1, sb);
    }

    // ---- online softmax (row r = 4*l4 + j, cols across 16-lane group) ----
    float p0[4], p1[4], sc[4];
    #pragma unroll
    for (int j = 0; j < 4; j++) {
      float mx = fmaxf(sa[j], sb[j]);
      mx = fmaxf(mx, __shfl_xor(mx, 1));
      mx = fmaxf(mx, __shfl_xor(mx, 2));
      mx = fmaxf(mx, __shfl_xor(mx, 4));
      mx = fmaxf(mx, __shfl_xor(mx, 8));
      float mn = fmaxf(mrow[j], mx);
      sc[j] = __expf(mrow[j] - mn);
      mrow[j] = mn;
      p0[j] = __expf(sa[j] - mn);
      p1[j] = __expf(sb[j] - mn);
      float rs = p0[j] + p1[j];
      rs += __shfl_xor(rs, 1);
      rs += __shfl_xor(rs, 2);
      rs += __shfl_xor(rs, 4);
      rs += __shfl_xor(rs, 8);
      lrow[j] = lrow[j] * sc[j] + rs;
    }
    #pragma unroll
    for (int i = 0; i < 16; i++) {
      O[i][0] *= sc[0]; O[i][1] *= sc[1]; O[i][2] *= sc[2]; O[i][3] *= sc[3];
    }

    // ---- P -> per-wave LDS (D-layout write, A-layout read), bf16 ----
    #pragma unroll
    for (int j = 0; j < 4; j++) {
      int row = l4 * 4 + j;
      int base = row << 6;
      int sw = (row & 7) << 4;
      *(u16*)(pw + ((base + l15 * 2) ^ sw)) = f2bf(p0[j]);
      *(u16*)(pw + ((base + (l15 + 16) * 2) ^ sw)) = f2bf(p1[j]);
    }
    asm volatile("s_waitcnt lgkmcnt(0)" ::: "memory");
    bf16x8 pa = *(const bf16x8*)(pw + (((l15 << 6) + kbyte) ^ ((l15 & 7) << 4)));

    // ---- PV: O += P * V (16 d-tiles) ----
    #pragma unroll
    for (int dt = 0; dt < 16; dt++) {
      int d = dt * 16 + l15;
      bf16x8 vb = *(const bf16x8*)(vt_lds + (((d << 6) + kbyte) ^ ((d & 7) << 4)));
      O[dt] = mfma16(pa, vb, O[dt]);
    }
  }

  // ---- epilogue: normalize + store fp32 ----
  float inv[4];
  #pragma unroll
  for (int j = 0; j < 4; j++) inv[j] = 1.0f / lrow[j];
  #pragma unroll
  for (int dt = 0; dt < 16; dt++) {
    #pragma unroll
    for (int j = 0; j < 4; j++) {
      size_t orow = (size_t)(b * 1024 + q0 + l4 * 4 + j);
      out[(orow << 8) + dt * 16 + l15] = O[dt][j] * inv[j];
    }
  }
}

// ============================================================
extern "C" void kernel_launch(void* const* d_in, const int* in_sizes, int n_in,
                              void* d_out, int out_size, void* d_ws, size_t ws_size,
                              hipStream_t stream) {
  (void)in_sizes; (void)n_in; (void)out_size; (void)ws_size;
  const float* x  = (const float*)d_in[0];
  const float* Wq = (const float*)d_in[1];
  const float* bq = (const float*)d_in[2];
  const float* Wk = (const float*)d_in[3];
  const float* bk = (const float*)d_in[4];
  const float* Wv = (const float*)d_in[5];
  const float* bv = (const float*)d_in[6];
  float* out = (float*)d_out;
  char* ws = (char*)d_ws;

  const size_t NQ = (size_t)64 * 1024 * 256;   // 16777216 elements
  u16* qh  = (u16*)(ws);
  u16* ql  = (u16*)(ws + 2 * NQ);
  u16* kh  = (u16*)(ws + 4 * NQ);
  u16* kl  = (u16*)(ws + 6 * NQ);
  u16* vt  = (u16*)(ws + 8 * NQ);
  u16* wsp = (u16*)(ws + 10 * NQ);             // 6 x 65536 u16 = 768KB

  prep_w_kernel<<<dim3(768), dim3(256), 0, stream>>>(Wq, Wk, Wv, wsp);
  proj_kernel<<<dim3(1024), dim3(256), 0, stream>>>(
      x, bq, bk, bv,
      wsp, wsp + 65536, wsp + 131072, wsp + 196608, wsp + 262144, wsp + 327680,
      qh, ql, kh, kl, vt);
  attn_kernel<<<dim3(16, 64), dim3(256), 0, stream>>>(qh, ql, kh, kl, vt, out);
}

// Round 2
// 473.601 us; speedup vs baseline: 1.5625x; 1.5625x over previous
//
#include <hip/hip_runtime.h>

typedef unsigned short u16;
typedef __attribute__((ext_vector_type(8))) __bf16 bf16x8;
typedef __attribute__((ext_vector_type(4))) float f32x4;

// ---------- bf16 split helpers ----------
static __device__ __forceinline__ u16 f2bf(float f) {
  union { float f; unsigned u; } v; v.f = f;
  unsigned r = v.u + 0x7FFFu + ((v.u >> 16) & 1u);   // RNE
  return (u16)(r >> 16);
}
static __device__ __forceinline__ float bf2f(u16 h) {
  union { unsigned u; float f; } v; v.u = ((unsigned)h) << 16;
  return v.f;
}
static __device__ __forceinline__ f32x4 mfma16(bf16x8 a, bf16x8 b, f32x4 c) {
  return __builtin_amdgcn_mfma_f32_16x16x32_bf16(a, b, c, 0, 0, 0);
}

// ============================================================
// Kernel 1: W^T hi/lo split into staging-ready swizzled layout.
// Per matrix: [colhalf 2][khalf 2][row 128][512B row: hi|lo interleaved at
// 16B-slot granularity, slot' = (slot + 2*row) & 31 (hi slots 0-15 source,
// lo at +16)]. 256KB per matrix. Linear 64KB block = one (colhalf,khalf).
// ============================================================
__global__ __launch_bounds__(256) void prep_w_kernel(
    const float* __restrict__ Wq, const float* __restrict__ Wk,
    const float* __restrict__ Wv, u16* __restrict__ wout) {
  int idx = blockIdx.x * 256 + threadIdx.x;   // 0..196607
  int mm = idx >> 16;
  int o  = idx & 65535;
  int row = o >> 8, e = o & 255;              // row = out-col of W^T, e = K idx
  const float* W = (mm == 0) ? Wq : ((mm == 1) ? Wk : Wv);
  float v = W[e * 256 + row];
  u16 hi = f2bf(v);
  u16 lo = f2bf(v - bf2f(hi));
  int ch = row >> 7, rl = row & 127;
  int kh2 = e >> 7, el = e & 127;
  int slot = el >> 3;                          // 0..15
  int sh  = (slot + 2 * rl) & 31;
  int sl2 = (slot + 16 + 2 * rl) & 31;
  size_t b0 = (size_t)mm * 262144 + (size_t)ch * 131072 + (size_t)kh2 * 65536
            + rl * 512 + (el & 7) * 2;
  *(u16*)((char*)wout + b0 + sh * 16) = hi;
  *(u16*)((char*)wout + b0 + sl2 * 16) = lo;
}

// ============================================================
// Kernel 2: QKV projection, weights resident in LDS.
// Grid: 1536 blocks x 512 thr. Block = (mt 0..5, token-chunk c 0..255):
//   mt 0,1: Q colhalves; 2,3: K colhalves; 4,5: V d-halves. 256 tokens/chunk.
// XCD swizzle: same token-chunk groups on same XCD (x L2 reuse).
// Two K-passes (khalf), 64KB weight LDS, additive swizzle (2-way, free).
// Wave: 64 tokens (4 tiles) x 64 cols (4 tiles); acc 64 VGPR.
// 3-term split MFMA. Outputs:
//   qh/ql [tok][256] plain; kh/kl [tok][256] col-swizzled (slot+2*tok);
//   vt tiled [b][tile32][256d][32t] bf16 with XOR d-swizzle.
// ============================================================
__global__ __launch_bounds__(512, 2) void proj_kernel(
    const float* __restrict__ x, const float* __restrict__ bq,
    const float* __restrict__ bk, const float* __restrict__ bv,
    const u16* __restrict__ wspl,
    u16* __restrict__ qh, u16* __restrict__ ql,
    u16* __restrict__ kh, u16* __restrict__ kl,
    u16* __restrict__ vt) {
  __shared__ __align__(16) char wlds[65536];
  const int tid = threadIdx.x;
  const int l = tid & 63, w = tid >> 6;       // wave 0..7
  const int l15 = l & 15, l4 = l >> 4;
  int wg = blockIdx.x;
  int g = wg >> 3;
  int mt = g % 6;
  int c = (g / 6) * 8 + (wg & 7);             // token chunk 0..255
  int mat = (mt < 4) ? (mt >> 1) : 2;         // 0=q 1=k 2=v
  int half = (mt < 4) ? (mt & 1) : (mt - 4);
  const int tokbase = c * 256;
  const int tg = w >> 1, cg = w & 1;
  const bool vm = (mat == 2);

  // per-tt token row and x base pointer
  const float* xp[4];
  #pragma unroll
  for (int tt = 0; tt < 4; tt++) {
    size_t tok = (size_t)tokbase + tg * 64 + tt * 16 + l15;
    xp[tt] = x + tok * 256;
  }

  f32x4 acc[4][4];
  #pragma unroll
  for (int a = 0; a < 4; a++)
    #pragma unroll
    for (int b2 = 0; b2 < 4; b2++) acc[a][b2] = (f32x4){0.f, 0.f, 0.f, 0.f};

  for (int khalf = 0; khalf < 2; khalf++) {
    if (khalf) __syncthreads();
    // stage 64KB weight slab (linear copy; swizzle pre-applied by prep)
    {
      const char* wsrc = (const char*)wspl + (size_t)mat * 262144
                       + (size_t)half * 131072 + (size_t)khalf * 65536;
      #pragma unroll
      for (int i = 0; i < 8; i++) {
        int cc = (tid + i * 512) * 16;
        *(int4*)(wlds + cc) = *(const int4*)(wsrc + cc);
      }
    }
    __syncthreads();

    #pragma unroll
    for (int kkl = 0; kkl < 4; kkl++) {
      // x fragments: load fp32, split hi/lo
      bf16x8 xh8[4], xl8[4];
      #pragma unroll
      for (int tt = 0; tt < 4; tt++) {
        const float* p = xp[tt] + khalf * 128 + kkl * 32 + l4 * 8;
        float4 f0 = *(const float4*)p;
        float4 f1 = *(const float4*)(p + 4);
        float ff[8] = {f0.x, f0.y, f0.z, f0.w, f1.x, f1.y, f1.z, f1.w};
        union { u16 s[8]; bf16x8 v; } H, L;
        #pragma unroll
        for (int e = 0; e < 8; e++) {
          u16 h = f2bf(ff[e]);
          H.s[e] = h;
          L.s[e] = f2bf(ff[e] - bf2f(h));
        }
        xh8[tt] = H.v; xl8[tt] = L.v;
      }
      #pragma unroll
      for (int ct = 0; ct < 4; ct++) {
        int r = cg * 64 + ct * 16 + l15;       // local weight row 0..127
        int sbase = (kkl << 2) + l4;           // hi slot 0..15
        int offh = r * 512 + (((sbase + 2 * r) & 31) << 4);
        int offl = r * 512 + (((sbase + 16 + 2 * r) & 31) << 4);
        bf16x8 bh = *(const bf16x8*)(wlds + offh);
        bf16x8 bl = *(const bf16x8*)(wlds + offl);
        #pragma unroll
        for (int tt = 0; tt < 4; tt++) {
          if (!vm) {
            acc[tt][ct] = mfma16(xh8[tt], bh, acc[tt][ct]);
            acc[tt][ct] = mfma16(xl8[tt], bh, acc[tt][ct]);
            acc[tt][ct] = mfma16(xh8[tt], bl, acc[tt][ct]);
          } else {
            acc[tt][ct] = mfma16(bh, xh8[tt], acc[tt][ct]);
            acc[tt][ct] = mfma16(bl, xh8[tt], acc[tt][ct]);
            acc[tt][ct] = mfma16(bh, xl8[tt], acc[tt][ct]);
          }
        }
      }
    }
  }

  // ---- epilogues ----
  if (!vm) {
    const float* bias = mat ? bk : bq;
    u16* oh = mat ? kh : qh;
    u16* ol = mat ? kl : ql;
    #pragma unroll
    for (int ct = 0; ct < 4; ct++) {
      int col = half * 128 + cg * 64 + ct * 16 + l15;
      float bb = bias[col];
      #pragma unroll
      for (int tt = 0; tt < 4; tt++) {
        #pragma unroll
        for (int j = 0; j < 4; j++) {
          size_t tok = (size_t)tokbase + tg * 64 + tt * 16 + l4 * 4 + j;
          float v = acc[tt][ct][j] + bb;
          u16 hi = f2bf(v);
          u16 lo = f2bf(v - bf2f(hi));
          size_t ci;
          if (mat == 0) ci = col;
          else ci = (size_t)((((col >> 3) + 2 * (int)tok) & 31) << 3) | (col & 7);
          oh[tok * 256 + ci] = hi;
          ol[tok * 256 + ci] = lo;
        }
      }
    }
  } else {
    #pragma unroll
    for (int ct = 0; ct < 4; ct++) {
      #pragma unroll
      for (int tt = 0; tt < 4; tt++) {
        int t = tokbase + tg * 64 + tt * 16 + l15;
        int bb2 = t >> 10, tile = (t >> 5) & 31, trel = t & 31;
        size_t tbase = ((size_t)(bb2 * 32 + tile)) * 16384;
        #pragma unroll
        for (int j = 0; j < 4; j++) {
          int d = half * 128 + cg * 64 + ct * 16 + l4 * 4 + j;
          float v = acc[tt][ct][j] + bv[d];
          size_t off = tbase
              + ((((d << 6) + ((trel >> 3) << 4)) ^ ((d & 7) << 4)) + ((trel & 7) << 1));
          *(u16*)((char*)vt + off) = f2bf(v);
        }
      }
    }
  }
}

// ============================================================
// Kernel 3: flash attention (unscaled, non-causal).
// Grid: 512 blocks x 512 thr. Block = 128 q rows (8 waves x 16), KVBLK=32.
// XCD swizzle: all 8 q-blocks of a batch on one XCD (K/V L2-resident).
// Staging = pure linear 16B copies (K swizzle + V tiling pre-applied).
// ============================================================
__global__ __launch_bounds__(512, 2) void attn_kernel(
    const u16* __restrict__ qh_g, const u16* __restrict__ ql_g,
    const u16* __restrict__ kh_g, const u16* __restrict__ kl_g,
    const u16* __restrict__ vt_g, float* __restrict__ out) {
  __shared__ __align__(16) char lds[57344];
  char* kh_lds = lds;            // [32][512B] additive-swizzled
  char* kl_lds = lds + 16384;
  char* vt_lds = lds + 32768;    // tiled V [256d][64B] XOR-swizzled
  char* p_lds  = lds + 49152;    // 8 waves x 1KB

  const int tid = threadIdx.x;
  const int l = tid & 63, w = tid >> 6;   // w 0..7
  const int l15 = l & 15, l4 = l >> 4;
  int wg = blockIdx.x;
  int b  = (wg & 7) * 8 + ((wg >> 3) >> 3);
  int qt = (wg >> 3) & 7;
  const int kbyte = l4 * 16;

  // ---- Q fragments (16 rows/wave, hi/lo) ----
  const int q0 = qt * 128 + w * 16;
  const size_t qtok = (size_t)(b * 1024 + q0 + l15);
  const u16* qhp = qh_g + (qtok << 8) + l4 * 8;
  const u16* qlp = ql_g + (qtok << 8) + l4 * 8;
  bf16x8 qfh[8], qfl[8];
  #pragma unroll
  for (int kk = 0; kk < 8; kk++) {
    qfh[kk] = *(const bf16x8*)(qhp + kk * 32);
    qfl[kk] = *(const bf16x8*)(qlp + kk * 32);
  }

  f32x4 O[16];
  #pragma unroll
  for (int i = 0; i < 16; i++) O[i] = (f32x4){0.f, 0.f, 0.f, 0.f};
  float mrow[4] = {-1e30f, -1e30f, -1e30f, -1e30f};
  float lrow[4] = {0.f, 0.f, 0.f, 0.f};

  const char* khb = (const char*)(kh_g + ((size_t)b << 18));
  const char* klb = (const char*)(kl_g + ((size_t)b << 18));
  const char* vtb = (const char*)(vt_g + ((size_t)b << 18));
  char* pw = p_lds + w * 1024;

  for (int t0 = 0; t0 < 1024; t0 += 32) {
    __syncthreads();
    // ---- stage K hi/lo + V tile: pure linear copies ----
    {
      const char* ks = khb + t0 * 512;
      const char* ls = klb + t0 * 512;
      const char* vs = vtb + (t0 >> 5) * 16384;
      #pragma unroll
      for (int i = 0; i < 2; i++) {
        int cc = (tid + i * 512) * 16;
        *(int4*)(kh_lds + cc) = *(const int4*)(ks + cc);
        *(int4*)(kl_lds + cc) = *(const int4*)(ls + cc);
        *(int4*)(vt_lds + cc) = *(const int4*)(vs + cc);
      }
    }
    __syncthreads();

    // ---- scores: S[16q][32t], 3-term split ----
    f32x4 sa = (f32x4){0.f, 0.f, 0.f, 0.f};
    f32x4 sb = (f32x4){0.f, 0.f, 0.f, 0.f};
    #pragma unroll
    for (int kk = 0; kk < 8; kk++) {
      int slot = (kk << 2) + l4;     // 0..31 hmm: kk*4 + l4 within 32 slots
      int r0 = l15, r1 = l15 + 16;
      int o0 = (r0 << 9) + (((slot + 2 * r0) & 31) << 4);
      int o1 = (r1 << 9) + (((slot + 2 * r1) & 31) << 4);
      bf16x8 bh0 = *(const bf16x8*)(kh_lds + o0);
      bf16x8 bl0 = *(const bf16x8*)(kl_lds + o0);
      bf16x8 bh1 = *(const bf16x8*)(kh_lds + o1);
      bf16x8 bl1 = *(const bf16x8*)(kl_lds + o1);
      sa = mfma16(qfh[kk], bh0, sa);
      sa = mfma16(qfl[kk], bh0, sa);
      sa = mfma16(qfh[kk], bl0, sa);
      sb = mfma16(qfh[kk], bh1, sb);
      sb = mfma16(qfl[kk], bh1, sb);
      sb = mfma16(qfh[kk], bl1, sb);
    }

    // ---- online softmax ----
    float p0[4], p1[4], sc[4];
    #pragma unroll
    for (int j = 0; j < 4; j++) {
      float mx = fmaxf(sa[j], sb[j]);
      mx = fmaxf(mx, __shfl_xor(mx, 1));
      mx = fmaxf(mx, __shfl_xor(mx, 2));
      mx = fmaxf(mx, __shfl_xor(mx, 4));
      mx = fmaxf(mx, __shfl_xor(mx, 8));
      float mn = fmaxf(mrow[j], mx);
      sc[j] = __expf(mrow[j] - mn);
      mrow[j] = mn;
      p0[j] = __expf(sa[j] - mn);
      p1[j] = __expf(sb[j] - mn);
      float rs = p0[j] + p1[j];
      rs += __shfl_xor(rs, 1);
      rs += __shfl_xor(rs, 2);
      rs += __shfl_xor(rs, 4);
      rs += __shfl_xor(rs, 8);
      lrow[j] = lrow[j] * sc[j] + rs;
    }
    #pragma unroll
    for (int i = 0; i < 16; i++) {
      O[i][0] *= sc[0]; O[i][1] *= sc[1]; O[i][2] *= sc[2]; O[i][3] *= sc[3];
    }

    // ---- P -> per-wave LDS (bf16), re-fragment for PV ----
    #pragma unroll
    for (int j = 0; j < 4; j++) {
      int row = l4 * 4 + j;
      int base = row << 6;
      int sw = (row & 7) << 4;
      *(u16*)(pw + ((base + l15 * 2) ^ sw)) = f2bf(p0[j]);
      *(u16*)(pw + ((base + (l15 + 16) * 2) ^ sw)) = f2bf(p1[j]);
    }
    asm volatile("s_waitcnt lgkmcnt(0)" ::: "memory");
    __builtin_amdgcn_sched_barrier(0);
    bf16x8 pa = *(const bf16x8*)(pw + (((l15 << 6) + kbyte) ^ ((l15 & 7) << 4)));

    // ---- PV: O += P * V ----
    #pragma unroll
    for (int dt = 0; dt < 16; dt++) {
      int d = dt * 16 + l15;
      bf16x8 vb = *(const bf16x8*)(vt_lds + (((d << 6) + kbyte) ^ ((d & 7) << 4)));
      O[dt] = mfma16(pa, vb, O[dt]);
    }
  }

  // ---- epilogue ----
  float inv[4];
  #pragma unroll
  for (int j = 0; j < 4; j++) inv[j] = 1.0f / lrow[j];
  #pragma unroll
  for (int dt = 0; dt < 16; dt++) {
    #pragma unroll
    for (int j = 0; j < 4; j++) {
      size_t orow = (size_t)(b * 1024 + q0 + l4 * 4 + j);
      out[(orow << 8) + dt * 16 + l15] = O[dt][j] * inv[j];
    }
  }
}

// ============================================================
extern "C" void kernel_launch(void* const* d_in, const int* in_sizes, int n_in,
                              void* d_out, int out_size, void* d_ws, size_t ws_size,
                              hipStream_t stream) {
  (void)in_sizes; (void)n_in; (void)out_size; (void)ws_size;
  const float* x  = (const float*)d_in[0];
  const float* Wq = (const float*)d_in[1];
  const float* bq = (const float*)d_in[2];
  const float* Wk = (const float*)d_in[3];
  const float* bk = (const float*)d_in[4];
  const float* Wv = (const float*)d_in[5];
  const float* bv = (const float*)d_in[6];
  float* out = (float*)d_out;
  char* ws = (char*)d_ws;

  u16* qh  = (u16*)(ws);
  u16* ql  = (u16*)(ws + 33554432);
  u16* kh  = (u16*)(ws + 67108864);
  u16* kl  = (u16*)(ws + 100663296);
  u16* vt  = (u16*)(ws + 134217728);
  u16* wsp = (u16*)(ws + 167772160);   // 768KB swizzled weights

  prep_w_kernel<<<dim3(768), dim3(256), 0, stream>>>(Wq, Wk, Wv, wsp);
  proj_kernel<<<dim3(1536), dim3(512), 0, stream>>>(
      x, bq, bk, bv, wsp, qh, ql, kh, kl, vt);
  attn_kernel<<<dim3(512), dim3(512), 0, stream>>>(qh, ql, kh, kl, vt, out);
}